// Round 2
// 587.265 us; speedup vs baseline: 1.3424x; 1.3424x over previous
//
#include <hip/hip_runtime.h>
#include <hip/hip_bf16.h>

#define BB 4
#define SS 1024
#define FF 1024
#define HH 16
#define DH 64

typedef short bf16x8 __attribute__((ext_vector_type(8)));
typedef float f32x4 __attribute__((ext_vector_type(4)));

__device__ __forceinline__ float b2f(unsigned short u) {
    union { unsigned int i; float f; } x; x.i = ((unsigned int)u) << 16; return x.f;
}
__device__ __forceinline__ unsigned short f2b(float f) {
    unsigned int x = __float_as_uint(f);
    unsigned int r = (x + 0x7fffu + ((x >> 16) & 1u)) >> 16;
    return (unsigned short)r;
}

// ---------------- fp32 -> bf16 conversion (x only) ----------------
__global__ void cvt_k(const float* __restrict__ in, unsigned short* __restrict__ out, int n) {
    int i = (blockIdx.x * blockDim.x + threadIdx.x) * 4;
    if (i < n) {
        float4 v = *(const float4*)(in + i);
        ushort4 o;
        o.x = f2b(v.x); o.y = f2b(v.y); o.z = f2b(v.z); o.w = f2b(v.w);
        *(ushort4*)(out + i) = o;
    }
}

// ---------------- fp32 W[k][n] -> bf16 Wt[n][k], LDS-tiled 32x32 ----------------
// grid (1024 tiles, 4 weights), 256 threads
__global__ void cvtT_k(const float* __restrict__ W0, const float* __restrict__ W1,
                       const float* __restrict__ W2, const float* __restrict__ W3,
                       unsigned short* __restrict__ out) {
    int y = blockIdx.y;
    const float* src = (y == 0) ? W0 : (y == 1) ? W1 : (y == 2) ? W2 : W3;
    unsigned short* dst = out + (size_t)y * FF * FF;
    __shared__ float t[32][33];
    int tile = blockIdx.x;
    int tk = (tile & 31) * 32, tn = (tile >> 5) * 32;
    int r = threadIdx.x >> 3, c4 = (threadIdx.x & 7) * 4;
    float4 v = *(const float4*)&src[(size_t)(tk + r) * FF + tn + c4];
    t[r][c4 + 0] = v.x; t[r][c4 + 1] = v.y; t[r][c4 + 2] = v.z; t[r][c4 + 3] = v.w;
    __syncthreads();
    ushort4 o;
    o.x = f2b(t[c4 + 0][r]); o.y = f2b(t[c4 + 1][r]);
    o.z = f2b(t[c4 + 2][r]); o.w = f2b(t[c4 + 3][r]);
    *(ushort4*)&dst[(size_t)(tn + r) * FF + tk + c4] = o;
}

// ---------------- V[bh][s][d] -> Vt[bh][d][s], conflict-free via uint-expanded LDS ----------------
// grid (16, 64), 256 threads
__global__ void vtrans_k(const unsigned short* __restrict__ V, unsigned short* __restrict__ Vt) {
    int bh = blockIdx.y;
    int sb = blockIdx.x * 64;
    size_t slab = (size_t)bh * SS * DH;
    __shared__ unsigned int tI[64][65];
    int tid = threadIdx.x;
    #pragma unroll
    for (int v = 0; v < 2; v++) {
        int c = tid + v * 256;
        int row = c >> 3, col = (c & 7) * 8;    // row = s_local, col = d
        uint4 u = *(const uint4*)&V[slab + (size_t)(sb + row) * DH + col];
        const unsigned short* us = (const unsigned short*)&u;
        #pragma unroll
        for (int j = 0; j < 8; j++) tI[row][col + j] = us[j];
    }
    __syncthreads();
    #pragma unroll
    for (int v = 0; v < 2; v++) {
        int c = tid + v * 256;
        int drow = c >> 3, scol = (c & 7) * 8;  // drow = d, scol = s_local base
        unsigned short o[8];
        #pragma unroll
        for (int j = 0; j < 8; j++) o[j] = (unsigned short)tI[scol + j][drow];
        *(uint4*)&Vt[slab + (size_t)drow * SS + sb + scol] = *(uint4*)o;
    }
}

// ---------------- 128x128 MFMA GEMM: C = A @ Wt^T + bias (Wt is [n][k]) ----------------
// BK=64, double-buffered LDS, 1 barrier per k-step.
#define LDK 72   // 64 + 8 pad (144 B stride: 16B-aligned, conflict-free b128 frags)
__global__ __launch_bounds__(256, 1) void gemm_k(
    const unsigned short* __restrict__ A, const unsigned short* __restrict__ Wt,
    const float* __restrict__ bias,
    unsigned short* __restrict__ o16, float* __restrict__ o32, float scale, int mode)
{
    __shared__ __attribute__((aligned(16))) unsigned short lA[2][128 * LDK];
    __shared__ __attribute__((aligned(16))) unsigned short lB[2][128 * LDK];

    int tid = threadIdx.x;
    int wave = tid >> 6, lane = tid & 63, quad = lane >> 4, l16 = lane & 15;
    int wm = (wave & 1) * 64, wn = (wave >> 1) * 64;
    int mbase = blockIdx.x * 128, nbase = blockIdx.y * 128;
    int srow = tid >> 3, scol = (tid & 7) * 8;   // staging: rows srow + i*32, cols scol..scol+7

    f32x4 acc[4][4];
    #pragma unroll
    for (int i = 0; i < 4; i++)
        #pragma unroll
        for (int j = 0; j < 4; j++) acc[i][j] = (f32x4){0.f, 0.f, 0.f, 0.f};

    const unsigned short* pA = A  + (size_t)(mbase + srow) * FF + scol;
    const unsigned short* pB = Wt + (size_t)(nbase + srow) * FF + scol;

    uint4 ra[4], rb[4];
    #pragma unroll
    for (int i = 0; i < 4; i++) {
        ra[i] = *(const uint4*)(pA + (size_t)i * 32 * FF);
        rb[i] = *(const uint4*)(pB + (size_t)i * 32 * FF);
    }
    #pragma unroll
    for (int i = 0; i < 4; i++) {
        *(uint4*)&lA[0][(srow + i * 32) * LDK + scol] = ra[i];
        *(uint4*)&lB[0][(srow + i * 32) * LDK + scol] = rb[i];
    }
    __syncthreads();

    for (int kt = 0; kt < 16; kt++) {
        int cur = kt & 1;
        // prefetch next K-slab into registers (latency hidden under MFMA phase)
        if (kt < 15) {
            #pragma unroll
            for (int i = 0; i < 4; i++) {
                ra[i] = *(const uint4*)(pA + (kt + 1) * 64 + (size_t)i * 32 * FF);
                rb[i] = *(const uint4*)(pB + (kt + 1) * 64 + (size_t)i * 32 * FF);
            }
        }
        #pragma unroll
        for (int ks = 0; ks < 2; ks++) {
            bf16x8 af[4], bfr[4];
            #pragma unroll
            for (int mi = 0; mi < 4; mi++)
                af[mi] = *(const bf16x8*)(&lA[cur][(wm + mi * 16 + l16) * LDK + ks * 32 + quad * 8]);
            #pragma unroll
            for (int ni = 0; ni < 4; ni++)
                bfr[ni] = *(const bf16x8*)(&lB[cur][(wn + ni * 16 + l16) * LDK + ks * 32 + quad * 8]);
            #pragma unroll
            for (int mi = 0; mi < 4; mi++)
                #pragma unroll
                for (int ni = 0; ni < 4; ni++)
                    acc[mi][ni] = __builtin_amdgcn_mfma_f32_16x16x32_bf16(af[mi], bfr[ni], acc[mi][ni], 0, 0, 0);
        }
        if (kt < 15) {
            #pragma unroll
            for (int i = 0; i < 4; i++) {
                *(uint4*)&lA[cur ^ 1][(srow + i * 32) * LDK + scol] = ra[i];
                *(uint4*)&lB[cur ^ 1][(srow + i * 32) * LDK + scol] = rb[i];
            }
        }
        __syncthreads();
    }

    // epilogue
    #pragma unroll
    for (int mi = 0; mi < 4; mi++) {
        #pragma unroll
        for (int ni = 0; ni < 4; ni++) {
            int col = nbase + wn + ni * 16 + l16;
            float bv = bias[col];
            #pragma unroll
            for (int r = 0; r < 4; r++) {
                int row = mbase + wm + mi * 16 + quad * 4 + r;
                float v = (acc[mi][ni][r] + bv) * scale;
                if (mode == 1) {
                    int b_ = row >> 10, i = row & 1023;
                    int h = i >> 6, s_ = ((i & 63) << 4) + (col >> 6), d = col & 63;
                    o16[(((size_t)(b_ * HH + h)) * SS + s_) * DH + d] = f2b(v);
                } else {
                    o32[(size_t)row * FF + col] = v;
                }
            }
        }
    }
}

// ---------------- per-row stats of masked str rows (fp32 in) ----------------
__global__ void rowstats_k(const float* __restrict__ str,
                           float* __restrict__ rmax, float* __restrict__ rinv) {
    int row = blockIdx.x * 4 + (threadIdx.x >> 6);   // [0, B*H*S)
    int lane = threadIdx.x & 63;
    int r = row & (SS - 1);
    const float* p = str + (size_t)row * SS;
    float vals[16];
    float mx = -1e30f;
    #pragma unroll
    for (int i = 0; i < 4; i++) {
        int k0 = i * 256 + lane * 4;
        float4 u = *(const float4*)(&p[k0]);
        float uv[4] = {u.x, u.y, u.z, u.w};
        #pragma unroll
        for (int j = 0; j < 4; j++) {
            float v = (k0 + j <= r) ? uv[j] : -1e30f;
            vals[i * 4 + j] = v;
            mx = fmaxf(mx, v);
        }
    }
    #pragma unroll
    for (int d = 1; d < 64; d <<= 1) mx = fmaxf(mx, __shfl_xor(mx, d));
    float sum = 0.f;
    #pragma unroll
    for (int i = 0; i < 16; i++) sum += __expf(fminf(vals[i] - mx, 0.f));
    #pragma unroll
    for (int d = 1; d < 64; d <<= 1) sum += __shfl_xor(sum, d);
    if (lane == 0) { rmax[row] = mx; rinv[row] = 1.0f / sum; }
}

// ---------------- fused attention ----------------
// Q prescaled by 1/64. scores = QK^T + sm; full-row softmax; O = P@V.
// V consumed pre-transposed: Vt[bh][d][s]. Double-buffered K/V, 1 barrier/tile.
#define LDT 72   // 64 + 8 pad
__global__ __launch_bounds__(256, 2) void attn_k(
    const unsigned short* __restrict__ Q, const unsigned short* __restrict__ K,
    const unsigned short* __restrict__ Vt, const float* __restrict__ str,
    const float* __restrict__ rmax, const float* __restrict__ rinv,
    unsigned short* __restrict__ ctx)
{
    int bh = blockIdx.y;
    int b_ = bh >> 4, h = bh & 15;
    int qbase = blockIdx.x * 64;
    int tid = threadIdx.x;
    int wave = tid >> 6, lane = tid & 63, quad = lane >> 4, l16 = lane & 15;
    int srow = tid >> 3, scol = (tid & 7) * 8;

    __shared__ __attribute__((aligned(16))) unsigned short lQP[64 * LDT];   // Q staging, then P (per-wave rows)
    __shared__ __attribute__((aligned(16))) unsigned short lK[2][64 * LDT];
    __shared__ __attribute__((aligned(16))) unsigned short lV[2][64 * LDT]; // rows=d, cols=t

    const size_t slab = (size_t)bh * SS * DH;

    // prologue: stage Q, K tile0, V tile0 (all vectorized, conflict-free)
    #pragma unroll
    for (int v = 0; v < 2; v++) {
        int row = srow + v * 32;
        *(uint4*)&lQP[row * LDT + scol]   = *(const uint4*)&Q [slab + (size_t)(qbase + row) * DH + scol];
        *(uint4*)&lK[0][row * LDT + scol] = *(const uint4*)&K [slab + (size_t)row * DH + scol];
        *(uint4*)&lV[0][row * LDT + scol] = *(const uint4*)&Vt[slab + (size_t)row * SS + scol];
    }
    int q_loc0 = wave * 16 + quad * 4;
    float rm4[4], ri4[4];
    #pragma unroll
    for (int r = 0; r < 4; r++) {
        rm4[r] = rmax[bh * SS + qbase + q_loc0 + r];
        ri4[r] = rinv[bh * SS + qbase + q_loc0 + r];
    }
    __syncthreads();

    // Q fragments hoisted (lQP's Q-rows become dead per-wave -> reused for P)
    bf16x8 aq[2];
    #pragma unroll
    for (int ks = 0; ks < 2; ks++)
        aq[ks] = *(const bf16x8*)&lQP[(wave * 16 + l16) * LDT + ks * 32 + quad * 8];

    float m_st[4], l_st[4];
    f32x4 Oacc[4];
    #pragma unroll
    for (int r = 0; r < 4; r++) { m_st[r] = -1e30f; l_st[r] = 0.f; }
    #pragma unroll
    for (int ni = 0; ni < 4; ni++) Oacc[ni] = (f32x4){0.f, 0.f, 0.f, 0.f};

    const size_t strbase = (size_t)bh * SS * SS;
    unsigned short* lPw = &lQP[(wave * 16) * LDT];

    for (int tt = 0; tt < 16; tt++) {
        int cur = tt & 1;
        int tbase = tt * 64;
        bool need_sm = (tbase <= qbase + 63);   // block-uniform

        // str prefetch for THIS tile (issued before MFMA so QK covers latency)
        float sf[4][4];
        if (need_sm) {
            #pragma unroll
            for (int r = 0; r < 4; r++) {
                int q_abs = qbase + q_loc0 + r;
                int lim = q_abs - tbase;
                const float* pr = str + strbase + (size_t)q_abs * SS + tbase + l16;
                #pragma unroll
                for (int ni = 0; ni < 4; ni++)
                    sf[ni][r] = (ni * 16 + l16 <= lim) ? pr[ni * 16] : -1e30f;
            }
        }
        // next-tile K/V prefetch (global -> regs; LDS write deferred to end of tile)
        uint4 kst[2], vst[2];
        if (tt < 15) {
            #pragma unroll
            for (int v = 0; v < 2; v++) {
                int row = srow + v * 32;
                kst[v] = *(const uint4*)&K [slab + (size_t)(tbase + 64 + row) * DH + scol];
                vst[v] = *(const uint4*)&Vt[slab + (size_t)row * SS + tbase + 64 + scol];
            }
        }

        // S = Q @ K^T  (16x64 per wave)
        f32x4 sa[4];
        #pragma unroll
        for (int ni = 0; ni < 4; ni++) sa[ni] = (f32x4){0.f, 0.f, 0.f, 0.f};
        #pragma unroll
        for (int ks = 0; ks < 2; ks++) {
            #pragma unroll
            for (int ni = 0; ni < 4; ni++) {
                bf16x8 bk_ = *(const bf16x8*)&lK[cur][(ni * 16 + l16) * LDT + ks * 32 + quad * 8];
                sa[ni] = __builtin_amdgcn_mfma_f32_16x16x32_bf16(aq[ks], bk_, sa[ni], 0, 0, 0);
            }
        }

        // scores = S + sm ; online softmax (in place in sa)
        float tm[4];
        #pragma unroll
        for (int r = 0; r < 4; r++) tm[r] = -1e30f;
        #pragma unroll
        for (int ni = 0; ni < 4; ni++) {
            #pragma unroll
            for (int r = 0; r < 4; r++) {
                float v = sa[ni][r];
                if (need_sm)
                    v += __expf(fminf(sf[ni][r] - rm4[r], 0.f)) * ri4[r];  // invalid lanes: exp(-inf)=0
                sa[ni][r] = v;
                tm[r] = fmaxf(tm[r], v);
            }
        }
        #pragma unroll
        for (int r = 0; r < 4; r++) {
            float v = tm[r];
            v = fmaxf(v, __shfl_xor(v, 1));
            v = fmaxf(v, __shfl_xor(v, 2));
            v = fmaxf(v, __shfl_xor(v, 4));
            v = fmaxf(v, __shfl_xor(v, 8));
            tm[r] = v;
        }
        float alpha[4], rs[4];
        #pragma unroll
        for (int r = 0; r < 4; r++) {
            float mn = fmaxf(m_st[r], tm[r]);
            alpha[r] = __expf(fminf(m_st[r] - mn, 0.f));
            m_st[r] = mn;
            rs[r] = 0.f;
        }
        #pragma unroll
        for (int ni = 0; ni < 4; ni++)
            #pragma unroll
            for (int r = 0; r < 4; r++) {
                sa[ni][r] = __expf(fminf(sa[ni][r] - m_st[r], 0.f));
                rs[r] += sa[ni][r];
            }
        #pragma unroll
        for (int r = 0; r < 4; r++) {
            float v = rs[r];
            v += __shfl_xor(v, 1); v += __shfl_xor(v, 2);
            v += __shfl_xor(v, 4); v += __shfl_xor(v, 8);
            l_st[r] = l_st[r] * alpha[r] + v;
        }
        #pragma unroll
        for (int ni = 0; ni < 4; ni++)
            #pragma unroll
            for (int r = 0; r < 4; r++) Oacc[ni][r] *= alpha[r];

        // P -> LDS (wave-private region: no barrier, lgkmcnt only)
        #pragma unroll
        for (int ni = 0; ni < 4; ni++)
            #pragma unroll
            for (int r = 0; r < 4; r++)
                lPw[(quad * 4 + r) * LDT + ni * 16 + l16] = f2b(sa[ni][r]);

        // O += P @ V
        #pragma unroll
        for (int ks = 0; ks < 2; ks++) {
            bf16x8 pa = *(const bf16x8*)&lPw[l16 * LDT + ks * 32 + quad * 8];
            #pragma unroll
            for (int ni = 0; ni < 4; ni++) {
                bf16x8 bv = *(const bf16x8*)&lV[cur][(ni * 16 + l16) * LDT + ks * 32 + quad * 8];
                Oacc[ni] = __builtin_amdgcn_mfma_f32_16x16x32_bf16(pa, bv, Oacc[ni], 0, 0, 0);
            }
        }

        // write next tile's K/V into the other buffer (loads issued at top have landed)
        if (tt < 15) {
            #pragma unroll
            for (int v = 0; v < 2; v++) {
                int row = srow + v * 32;
                *(uint4*)&lK[cur ^ 1][row * LDT + scol] = kst[v];
                *(uint4*)&lV[cur ^ 1][row * LDT + scol] = vst[v];
            }
        }
        __syncthreads();
    }

    // epilogue: ctx[b][s][h*64+d]
    #pragma unroll
    for (int r = 0; r < 4; r++) {
        int s_abs = qbase + wave * 16 + quad * 4 + r;
        float li = 1.0f / l_st[r];
        #pragma unroll
        for (int ni = 0; ni < 4; ni++) {
            int d = ni * 16 + l16;
            ctx[((size_t)b_ * SS + s_abs) * FF + h * 64 + d] = f2b(Oacc[ni][r] * li);
        }
    }
}

extern "C" void kernel_launch(void* const* d_in, const int* in_sizes, int n_in,
                              void* d_out, int out_size, void* d_ws, size_t ws_size,
                              hipStream_t stream) {
    const float* x   = (const float*)d_in[0];
    const float* str = (const float*)d_in[1];
    const float* Wq  = (const float*)d_in[3];
    const float* bq  = (const float*)d_in[4];
    const float* Wk  = (const float*)d_in[5];
    const float* bk  = (const float*)d_in[6];
    const float* Wv  = (const float*)d_in[7];
    const float* bv  = (const float*)d_in[8];
    const float* Wo  = (const float*)d_in[9];
    const float* bo  = (const float*)d_in[10];

    // workspace layout (56.5 MB):
    //   xb   : 8 MB   (4M bf16)            [0, 8)
    //   Wt   : 8 MB   (4 x 1M bf16, [n][k]) [8, 16)
    //   QKV  : 24 MB  (3 x 4M bf16)        [16, 40)
    //   Vt   : 8 MB   (4M bf16, [bh][d][s]) [40, 48)
    //   ctx  : 8 MB   (4M bf16)            [48, 56)
    //   rmax : 256 KB (64K fp32)           [56, 56.25)
    //   rinv : 256 KB (64K fp32)           [56.25, 56.5)
    char* ws = (char*)d_ws;
    const size_t MB = 1024ull * 1024;
    unsigned short* xb  = (unsigned short*)ws;
    unsigned short* Wb  = (unsigned short*)(ws + 8 * MB);
    unsigned short* QKV = (unsigned short*)(ws + 16 * MB);
    unsigned short* Vtp = (unsigned short*)(ws + 40 * MB);
    unsigned short* ctx = (unsigned short*)(ws + 48 * MB);
    float* rmax = (float*)(ws + 56 * MB);
    float* rinv = (float*)(ws + 56 * MB + 256 * 1024);

    const size_t QN = (size_t)BB * SS * FF;   // 4M elems
    const size_t WN = (size_t)FF * FF;        // 1M elems

    cvt_k<<<4096, 256, 0, stream>>>(x, xb, (int)QN);
    cvtT_k<<<dim3(1024, 4), 256, 0, stream>>>(Wq, Wk, Wv, Wo, Wb);

    gemm_k<<<dim3(32, 8), 256, 0, stream>>>(xb, Wb,          bq, QKV,          nullptr, 0.015625f, 1);
    gemm_k<<<dim3(32, 8), 256, 0, stream>>>(xb, Wb + WN,     bk, QKV + QN,     nullptr, 1.0f,      1);
    gemm_k<<<dim3(32, 8), 256, 0, stream>>>(xb, Wb + 2 * WN, bv, QKV + 2 * QN, nullptr, 1.0f,      1);
    vtrans_k<<<dim3(16, 64), 256, 0, stream>>>(QKV + 2 * QN, Vtp);
    rowstats_k<<<16384, 256, 0, stream>>>(str, rmax, rinv);
    attn_k<<<dim3(16, 64), 256, 0, stream>>>(QKV, QKV + QN, Vtp, str, rmax, rinv, ctx);
    gemm_k<<<dim3(32, 8), 256, 0, stream>>>(ctx, Wb + 3 * WN, bo, nullptr, (float*)d_out, 1.0f, 0);
}

// Round 3
// 557.123 us; speedup vs baseline: 1.4150x; 1.0541x over previous
//
#include <hip/hip_runtime.h>
#include <hip/hip_bf16.h>

#define BB 4
#define SS 1024
#define FF 1024
#define HH 16
#define DH 64

typedef short bf16x8 __attribute__((ext_vector_type(8)));
typedef float f32x4 __attribute__((ext_vector_type(4)));

__device__ __forceinline__ float b2f(unsigned short u) {
    union { unsigned int i; float f; } x; x.i = ((unsigned int)u) << 16; return x.f;
}
__device__ __forceinline__ unsigned short f2b(float f) {
    unsigned int x = __float_as_uint(f);
    unsigned int r = (x + 0x7fffu + ((x >> 16) & 1u)) >> 16;
    return (unsigned short)r;
}
// T2 XOR swizzle for 64-elem (128 B) rows: flips elem bits 3..5 by row&7.
// Conflict-free for both b128 staging writes and b128 fragment reads.
__device__ __forceinline__ int sw(int row, int col) { return col ^ ((row & 7) << 3); }

// ---------------- fp32 -> bf16 conversion (x only) ----------------
__global__ void cvt_k(const float* __restrict__ in, unsigned short* __restrict__ out, int n) {
    int i = (blockIdx.x * blockDim.x + threadIdx.x) * 4;
    if (i < n) {
        float4 v = *(const float4*)(in + i);
        ushort4 o;
        o.x = f2b(v.x); o.y = f2b(v.y); o.z = f2b(v.z); o.w = f2b(v.w);
        *(ushort4*)(out + i) = o;
    }
}

// ---------------- fp32 W[k][n] -> bf16 Wt[n][k], LDS-tiled 32x32 ----------------
__global__ void cvtT_k(const float* __restrict__ W0, const float* __restrict__ W1,
                       const float* __restrict__ W2, const float* __restrict__ W3,
                       unsigned short* __restrict__ out) {
    int y = blockIdx.y;
    const float* src = (y == 0) ? W0 : (y == 1) ? W1 : (y == 2) ? W2 : W3;
    unsigned short* dst = out + (size_t)y * FF * FF;
    __shared__ float t[32][33];
    int tile = blockIdx.x;
    int tk = (tile & 31) * 32, tn = (tile >> 5) * 32;
    int r = threadIdx.x >> 3, c4 = (threadIdx.x & 7) * 4;
    float4 v = *(const float4*)&src[(size_t)(tk + r) * FF + tn + c4];
    t[r][c4 + 0] = v.x; t[r][c4 + 1] = v.y; t[r][c4 + 2] = v.z; t[r][c4 + 3] = v.w;
    __syncthreads();
    ushort4 o;
    o.x = f2b(t[c4 + 0][r]); o.y = f2b(t[c4 + 1][r]);
    o.z = f2b(t[c4 + 2][r]); o.w = f2b(t[c4 + 3][r]);
    *(ushort4*)&dst[(size_t)(tn + r) * FF + tk + c4] = o;
}

// ---------------- V[bh][s][d] -> Vt[bh][d][s] ----------------
__global__ void vtrans_k(const unsigned short* __restrict__ V, unsigned short* __restrict__ Vt) {
    int bh = blockIdx.y;
    int sb = blockIdx.x * 64;
    size_t slab = (size_t)bh * SS * DH;
    __shared__ unsigned int tI[64][65];
    int tid = threadIdx.x;
    #pragma unroll
    for (int v = 0; v < 2; v++) {
        int c = tid + v * 256;
        int row = c >> 3, col = (c & 7) * 8;
        uint4 u = *(const uint4*)&V[slab + (size_t)(sb + row) * DH + col];
        const unsigned short* us = (const unsigned short*)&u;
        #pragma unroll
        for (int j = 0; j < 8; j++) tI[row][col + j] = us[j];
    }
    __syncthreads();
    #pragma unroll
    for (int v = 0; v < 2; v++) {
        int c = tid + v * 256;
        int drow = c >> 3, scol = (c & 7) * 8;
        unsigned short o[8];
        #pragma unroll
        for (int j = 0; j < 8; j++) o[j] = (unsigned short)tI[scol + j][drow];
        *(uint4*)&Vt[slab + (size_t)drow * SS + sb + scol] = *(uint4*)o;
    }
}

// ---------------- 128x128 MFMA GEMM: C = A @ Wt^T + bias (Wt is [n][k]) ----------------
// BK=64, double-buffered swizzled LDS (stride 64, XOR), 1 barrier/k-step.
// mode 1: fused QKV (blockIdx.y selects matrix), bf16 scatter. mode 0: fp32 out.
__global__ __launch_bounds__(256, 1) void gemm_k(
    const unsigned short* __restrict__ A, const unsigned short* __restrict__ Wt,
    const float* __restrict__ b0, const float* __restrict__ b1, const float* __restrict__ b2,
    unsigned short* __restrict__ o16, float* __restrict__ o32, int mode)
{
    __shared__ __attribute__((aligned(16))) unsigned short lA[2][128 * 64];
    __shared__ __attribute__((aligned(16))) unsigned short lB[2][128 * 64];

    int tid = threadIdx.x;
    int wave = tid >> 6, lane = tid & 63, quad = lane >> 4, l16 = lane & 15;
    int wm = (wave & 1) * 64, wn = (wave >> 1) * 64;
    int mbase = blockIdx.x * 128;
    int srow = tid >> 3, scol = (tid & 7) * 8;

    int nbase;
    const float* bias;
    float scale = 1.0f;
    const unsigned short* W = Wt;
    unsigned short* oq = o16;
    if (mode == 1) {
        int widx = blockIdx.y >> 3;                 // 0=Q 1=K 2=V
        nbase = (blockIdx.y & 7) * 128;
        W = Wt + (size_t)widx * FF * FF;
        bias = (widx == 0) ? b0 : (widx == 1) ? b1 : b2;
        scale = (widx == 0) ? 0.015625f : 1.0f;
        oq = o16 + (size_t)widx * BB * SS * FF;
    } else {
        nbase = blockIdx.y * 128;
        bias = b0;
    }

    f32x4 acc[4][4];
    #pragma unroll
    for (int i = 0; i < 4; i++)
        #pragma unroll
        for (int j = 0; j < 4; j++) acc[i][j] = (f32x4){0.f, 0.f, 0.f, 0.f};

    const unsigned short* pA = A + (size_t)(mbase + srow) * FF + scol;
    const unsigned short* pB = W + (size_t)(nbase + srow) * FF + scol;

    uint4 ra[4], rb[4];
    #pragma unroll
    for (int i = 0; i < 4; i++) {
        ra[i] = *(const uint4*)(pA + (size_t)i * 32 * FF);
        rb[i] = *(const uint4*)(pB + (size_t)i * 32 * FF);
    }
    #pragma unroll
    for (int i = 0; i < 4; i++) {
        *(uint4*)&lA[0][(srow + i * 32) * 64 + sw(srow, scol)] = ra[i];
        *(uint4*)&lB[0][(srow + i * 32) * 64 + sw(srow, scol)] = rb[i];
    }
    __syncthreads();

    for (int kt = 0; kt < 16; kt++) {
        int cur = kt & 1;
        if (kt < 15) {
            #pragma unroll
            for (int i = 0; i < 4; i++) {
                ra[i] = *(const uint4*)(pA + (kt + 1) * 64 + (size_t)i * 32 * FF);
                rb[i] = *(const uint4*)(pB + (kt + 1) * 64 + (size_t)i * 32 * FF);
            }
        }
        #pragma unroll
        for (int ks = 0; ks < 2; ks++) {
            bf16x8 af[4], bfr[4];
            #pragma unroll
            for (int mi = 0; mi < 4; mi++) {
                int row = wm + mi * 16 + l16;
                af[mi] = *(const bf16x8*)(&lA[cur][row * 64 + sw(row, ks * 32 + quad * 8)]);
            }
            #pragma unroll
            for (int ni = 0; ni < 4; ni++) {
                int row = wn + ni * 16 + l16;
                bfr[ni] = *(const bf16x8*)(&lB[cur][row * 64 + sw(row, ks * 32 + quad * 8)]);
            }
            #pragma unroll
            for (int mi = 0; mi < 4; mi++)
                #pragma unroll
                for (int ni = 0; ni < 4; ni++)
                    acc[mi][ni] = __builtin_amdgcn_mfma_f32_16x16x32_bf16(af[mi], bfr[ni], acc[mi][ni], 0, 0, 0);
        }
        if (kt < 15) {
            #pragma unroll
            for (int i = 0; i < 4; i++) {
                *(uint4*)&lA[cur ^ 1][(srow + i * 32) * 64 + sw(srow, scol)] = ra[i];
                *(uint4*)&lB[cur ^ 1][(srow + i * 32) * 64 + sw(srow, scol)] = rb[i];
            }
        }
        __syncthreads();
    }

    // epilogue
    #pragma unroll
    for (int mi = 0; mi < 4; mi++) {
        #pragma unroll
        for (int ni = 0; ni < 4; ni++) {
            int col = nbase + wn + ni * 16 + l16;
            float bv = bias[col];
            #pragma unroll
            for (int r = 0; r < 4; r++) {
                int row = mbase + wm + mi * 16 + quad * 4 + r;
                float v = (acc[mi][ni][r] + bv) * scale;
                if (mode == 1) {
                    int b_ = row >> 10, i = row & 1023;
                    int h = i >> 6, s_ = ((i & 63) << 4) + (col >> 6), d = col & 63;
                    oq[(((size_t)(b_ * HH + h)) * SS + s_) * DH + d] = f2b(v);
                } else {
                    o32[(size_t)row * FF + col] = v;
                }
            }
        }
    }
}

// ---------------- per-row stats of masked str rows ----------------
__global__ void rowstats_k(const float* __restrict__ str,
                           float* __restrict__ rmax, float* __restrict__ rinv) {
    int row = blockIdx.x * 4 + (threadIdx.x >> 6);
    int lane = threadIdx.x & 63;
    int r = row & (SS - 1);
    const float* p = str + (size_t)row * SS;
    float vals[16];
    float mx = -1e30f;
    #pragma unroll
    for (int i = 0; i < 4; i++) {
        int k0 = i * 256 + lane * 4;
        float4 u = *(const float4*)(&p[k0]);
        float uv[4] = {u.x, u.y, u.z, u.w};
        #pragma unroll
        for (int j = 0; j < 4; j++) {
            float v = (k0 + j <= r) ? uv[j] : -1e30f;
            vals[i * 4 + j] = v;
            mx = fmaxf(mx, v);
        }
    }
    #pragma unroll
    for (int d = 1; d < 64; d <<= 1) mx = fmaxf(mx, __shfl_xor(mx, d));
    float sum = 0.f;
    #pragma unroll
    for (int i = 0; i < 16; i++) sum += __expf(fminf(vals[i] - mx, 0.f));
    #pragma unroll
    for (int d = 1; d < 64; d <<= 1) sum += __shfl_xor(sum, d);
    if (lane == 0) { rmax[row] = mx; rinv[row] = 1.0f / sum; }
}

// ---------------- fused attention ----------------
// Q prescaled by 1/64. scores = QK^T + sm; online softmax; O = P@V.
// Swizzled LDS (stride 64, XOR): conflict-free staging writes + frag reads.
__global__ __launch_bounds__(256, 2) void attn_k(
    const unsigned short* __restrict__ Q, const unsigned short* __restrict__ K,
    const unsigned short* __restrict__ Vt, const float* __restrict__ str,
    const float* __restrict__ rmax, const float* __restrict__ rinv,
    unsigned short* __restrict__ ctx)
{
    int bh = blockIdx.y;
    int b_ = bh >> 4, h = bh & 15;
    int qbase = blockIdx.x * 64;
    int tid = threadIdx.x;
    int wave = tid >> 6, lane = tid & 63, quad = lane >> 4, l16 = lane & 15;
    int srow = tid >> 3, scol = (tid & 7) * 8;

    __shared__ __attribute__((aligned(16))) unsigned short lQP[64 * 64];   // Q staging, then P (per-wave rows)
    __shared__ __attribute__((aligned(16))) unsigned short lK[2][64 * 64];
    __shared__ __attribute__((aligned(16))) unsigned short lV[2][64 * 64]; // rows=d, cols=t

    const size_t slab = (size_t)bh * SS * DH;

    #pragma unroll
    for (int v = 0; v < 2; v++) {
        int row = srow + v * 32;
        *(uint4*)&lQP[row * 64 + sw(row, scol)]   = *(const uint4*)&Q [slab + (size_t)(qbase + row) * DH + scol];
        *(uint4*)&lK[0][row * 64 + sw(row, scol)] = *(const uint4*)&K [slab + (size_t)row * DH + scol];
        *(uint4*)&lV[0][row * 64 + sw(row, scol)] = *(const uint4*)&Vt[slab + (size_t)row * SS + scol];
    }
    int q_loc0 = wave * 16 + quad * 4;
    float rm4[4], ri4[4];
    #pragma unroll
    for (int r = 0; r < 4; r++) {
        rm4[r] = rmax[bh * SS + qbase + q_loc0 + r];
        ri4[r] = rinv[bh * SS + qbase + q_loc0 + r];
    }
    __syncthreads();

    // Q fragments hoisted (lQP then reused as per-wave P buffer)
    bf16x8 aq[2];
    #pragma unroll
    for (int ks = 0; ks < 2; ks++) {
        int row = wave * 16 + l16;
        aq[ks] = *(const bf16x8*)&lQP[row * 64 + sw(row, ks * 32 + quad * 8)];
    }

    float m_st[4], l_st[4];
    f32x4 Oacc[4];
    #pragma unroll
    for (int r = 0; r < 4; r++) { m_st[r] = -1e30f; l_st[r] = 0.f; }
    #pragma unroll
    for (int ni = 0; ni < 4; ni++) Oacc[ni] = (f32x4){0.f, 0.f, 0.f, 0.f};

    const size_t strbase = (size_t)bh * SS * SS;
    unsigned short* lPw = &lQP[(wave * 16) * 64];

    for (int tt = 0; tt < 16; tt++) {
        int cur = tt & 1;
        int tbase = tt * 64;
        bool need_sm = (tbase <= qbase + 63);   // block-uniform

        // str loads for THIS tile (issued early; QK^T covers latency)
        float sf[4][4];
        if (need_sm) {
            #pragma unroll
            for (int r = 0; r < 4; r++) {
                int q_abs = qbase + q_loc0 + r;
                int lim = q_abs - tbase;
                const float* pr = str + strbase + (size_t)q_abs * SS + tbase + l16;
                #pragma unroll
                for (int ni = 0; ni < 4; ni++)
                    sf[ni][r] = (ni * 16 + l16 <= lim) ? pr[ni * 16] : -1e30f;
            }
        }
        // next-tile K/V prefetch (global -> regs; LDS write deferred)
        uint4 kst[2], vst[2];
        if (tt < 15) {
            #pragma unroll
            for (int v = 0; v < 2; v++) {
                int row = srow + v * 32;
                kst[v] = *(const uint4*)&K [slab + (size_t)(tbase + 64 + row) * DH + scol];
                vst[v] = *(const uint4*)&Vt[slab + (size_t)row * SS + tbase + 64 + scol];
            }
        }

        // S = Q @ K^T  (16x64 per wave)
        f32x4 sa[4];
        #pragma unroll
        for (int ni = 0; ni < 4; ni++) sa[ni] = (f32x4){0.f, 0.f, 0.f, 0.f};
        #pragma unroll
        for (int ks = 0; ks < 2; ks++) {
            #pragma unroll
            for (int ni = 0; ni < 4; ni++) {
                int row = ni * 16 + l16;
                bf16x8 bk_ = *(const bf16x8*)&lK[cur][row * 64 + sw(row, ks * 32 + quad * 8)];
                sa[ni] = __builtin_amdgcn_mfma_f32_16x16x32_bf16(aq[ks], bk_, sa[ni], 0, 0, 0);
            }
        }

        // scores = S + sm ; online softmax
        float tm[4];
        #pragma unroll
        for (int r = 0; r < 4; r++) tm[r] = -1e30f;
        #pragma unroll
        for (int ni = 0; ni < 4; ni++) {
            #pragma unroll
            for (int r = 0; r < 4; r++) {
                float v = sa[ni][r];
                if (need_sm)
                    v += __expf(fminf(sf[ni][r] - rm4[r], 0.f)) * ri4[r];
                sa[ni][r] = v;
                tm[r] = fmaxf(tm[r], v);
            }
        }
        #pragma unroll
        for (int r = 0; r < 4; r++) {
            float v = tm[r];
            v = fmaxf(v, __shfl_xor(v, 1));
            v = fmaxf(v, __shfl_xor(v, 2));
            v = fmaxf(v, __shfl_xor(v, 4));
            v = fmaxf(v, __shfl_xor(v, 8));
            tm[r] = v;
        }
        float alpha[4], rs[4];
        #pragma unroll
        for (int r = 0; r < 4; r++) {
            float mn = fmaxf(m_st[r], tm[r]);
            alpha[r] = __expf(fminf(m_st[r] - mn, 0.f));
            m_st[r] = mn;
            rs[r] = 0.f;
        }
        #pragma unroll
        for (int ni = 0; ni < 4; ni++)
            #pragma unroll
            for (int r = 0; r < 4; r++) {
                sa[ni][r] = __expf(fminf(sa[ni][r] - m_st[r], 0.f));
                rs[r] += sa[ni][r];
            }
        #pragma unroll
        for (int r = 0; r < 4; r++) {
            float v = rs[r];
            v += __shfl_xor(v, 1); v += __shfl_xor(v, 2);
            v += __shfl_xor(v, 4); v += __shfl_xor(v, 8);
            l_st[r] = l_st[r] * alpha[r] + v;
        }
        #pragma unroll
        for (int ni = 0; ni < 4; ni++)
            #pragma unroll
            for (int r = 0; r < 4; r++) Oacc[ni][r] *= alpha[r];

        // P -> LDS (wave-private rows; swizzled by local row)
        #pragma unroll
        for (int ni = 0; ni < 4; ni++)
            #pragma unroll
            for (int r = 0; r < 4; r++) {
                int pr = quad * 4 + r;
                lPw[pr * 64 + sw(pr, ni * 16 + l16)] = f2b(sa[ni][r]);
            }

        // O += P @ V
        #pragma unroll
        for (int ks = 0; ks < 2; ks++) {
            bf16x8 pa = *(const bf16x8*)&lPw[l16 * 64 + sw(l16, ks * 32 + quad * 8)];
            #pragma unroll
            for (int ni = 0; ni < 4; ni++) {
                int row = ni * 16 + l16;
                bf16x8 bv = *(const bf16x8*)&lV[cur][row * 64 + sw(row, ks * 32 + quad * 8)];
                Oacc[ni] = __builtin_amdgcn_mfma_f32_16x16x32_bf16(pa, bv, Oacc[ni], 0, 0, 0);
            }
        }

        if (tt < 15) {
            #pragma unroll
            for (int v = 0; v < 2; v++) {
                int row = srow + v * 32;
                *(uint4*)&lK[cur ^ 1][row * 64 + sw(row, scol)] = kst[v];
                *(uint4*)&lV[cur ^ 1][row * 64 + sw(row, scol)] = vst[v];
            }
        }
        __syncthreads();
    }

    // epilogue: ctx[b][s][h*64+d]
    #pragma unroll
    for (int r = 0; r < 4; r++) {
        int s_abs = qbase + wave * 16 + quad * 4 + r;
        float li = 1.0f / l_st[r];
        #pragma unroll
        for (int ni = 0; ni < 4; ni++) {
            int d = ni * 16 + l16;
            ctx[((size_t)b_ * SS + s_abs) * FF + h * 64 + d] = f2b(Oacc[ni][r] * li);
        }
    }
}

extern "C" void kernel_launch(void* const* d_in, const int* in_sizes, int n_in,
                              void* d_out, int out_size, void* d_ws, size_t ws_size,
                              hipStream_t stream) {
    const float* x   = (const float*)d_in[0];
    const float* str = (const float*)d_in[1];
    const float* Wq  = (const float*)d_in[3];
    const float* bq  = (const float*)d_in[4];
    const float* Wk  = (const float*)d_in[5];
    const float* bk  = (const float*)d_in[6];
    const float* Wv  = (const float*)d_in[7];
    const float* bv  = (const float*)d_in[8];
    const float* Wo  = (const float*)d_in[9];
    const float* bo  = (const float*)d_in[10];

    // workspace layout (56.5 MB)
    char* ws = (char*)d_ws;
    const size_t MB = 1024ull * 1024;
    unsigned short* xb  = (unsigned short*)ws;
    unsigned short* Wb  = (unsigned short*)(ws + 8 * MB);
    unsigned short* QKV = (unsigned short*)(ws + 16 * MB);
    unsigned short* Vtp = (unsigned short*)(ws + 40 * MB);
    unsigned short* ctx = (unsigned short*)(ws + 48 * MB);
    float* rmax = (float*)(ws + 56 * MB);
    float* rinv = (float*)(ws + 56 * MB + 256 * 1024);

    const size_t QN = (size_t)BB * SS * FF;   // 4M elems
    const size_t WN = (size_t)FF * FF;        // 1M elems

    cvt_k<<<4096, 256, 0, stream>>>(x, xb, (int)QN);
    cvtT_k<<<dim3(1024, 4), 256, 0, stream>>>(Wq, Wk, Wv, Wo, Wb);

    // fused QKV projection: one dispatch, 768 blocks
    gemm_k<<<dim3(32, 24), 256, 0, stream>>>(xb, Wb, bq, bk, bv, QKV, nullptr, 1);
    vtrans_k<<<dim3(16, 64), 256, 0, stream>>>(QKV + 2 * QN, Vtp);
    rowstats_k<<<16384, 256, 0, stream>>>(str, rmax, rinv);
    attn_k<<<dim3(16, 64), 256, 0, stream>>>(QKV, QKV + QN, Vtp, str, rmax, rinv, ctx);
    gemm_k<<<dim3(32, 8), 256, 0, stream>>>(ctx, Wb + 3 * WN, bo, nullptr, nullptr, nullptr, (float*)d_out, 0);
}

// Round 4
// 531.851 us; speedup vs baseline: 1.4823x; 1.0475x over previous
//
#include <hip/hip_runtime.h>
#include <hip/hip_bf16.h>

#define BB 4
#define SS 1024
#define FF 1024
#define HH 16
#define DH 64

typedef short bf16x8 __attribute__((ext_vector_type(8)));
typedef float f32x4 __attribute__((ext_vector_type(4)));

__device__ __forceinline__ float b2f(unsigned short u) {
    union { unsigned int i; float f; } x; x.i = ((unsigned int)u) << 16; return x.f;
}
__device__ __forceinline__ unsigned short f2b(float f) {
    unsigned int x = __float_as_uint(f);
    unsigned int r = (x + 0x7fffu + ((x >> 16) & 1u)) >> 16;
    return (unsigned short)r;
}
// T2 XOR swizzle for 64-elem (128 B) rows. Involution: applied on global src
// (staging) and on LDS read -> net identity, conflict-free both sides.
__device__ __forceinline__ int sw(int row, int col) { return col ^ ((row & 7) << 3); }

// async 16B global->LDS (direct, no VGPR round trip). LDS dest = wave-uniform
// base + lane*16; global src is per-lane.
__device__ __forceinline__ void async_copy16(void* lds, const void* g) {
    __builtin_amdgcn_global_load_lds(
        (const __attribute__((address_space(1))) unsigned int*)g,
        (__attribute__((address_space(3))) unsigned int*)lds, 16, 0, 0);
}

// ---------------- fp32 -> bf16 conversion (x only) ----------------
__global__ void cvt_k(const float* __restrict__ in, unsigned short* __restrict__ out, int n) {
    int i = (blockIdx.x * blockDim.x + threadIdx.x) * 4;
    if (i < n) {
        float4 v = *(const float4*)(in + i);
        ushort4 o;
        o.x = f2b(v.x); o.y = f2b(v.y); o.z = f2b(v.z); o.w = f2b(v.w);
        *(ushort4*)(out + i) = o;
    }
}

// ---------------- fp32 W[k][n] -> bf16 Wt[n][k], LDS-tiled 32x32 ----------------
__global__ void cvtT_k(const float* __restrict__ W0, const float* __restrict__ W1,
                       const float* __restrict__ W2, const float* __restrict__ W3,
                       unsigned short* __restrict__ out) {
    int y = blockIdx.y;
    const float* src = (y == 0) ? W0 : (y == 1) ? W1 : (y == 2) ? W2 : W3;
    unsigned short* dst = out + (size_t)y * FF * FF;
    __shared__ float t[32][33];
    int tile = blockIdx.x;
    int tk = (tile & 31) * 32, tn = (tile >> 5) * 32;
    int r = threadIdx.x >> 3, c4 = (threadIdx.x & 7) * 4;
    float4 v = *(const float4*)&src[(size_t)(tk + r) * FF + tn + c4];
    t[r][c4 + 0] = v.x; t[r][c4 + 1] = v.y; t[r][c4 + 2] = v.z; t[r][c4 + 3] = v.w;
    __syncthreads();
    ushort4 o;
    o.x = f2b(t[c4 + 0][r]); o.y = f2b(t[c4 + 1][r]);
    o.z = f2b(t[c4 + 2][r]); o.w = f2b(t[c4 + 3][r]);
    *(ushort4*)&dst[(size_t)(tn + r) * FF + tk + c4] = o;
}

// ---------------- V[bh][s][d] -> Vt[bh][d][s] ----------------
__global__ void vtrans_k(const unsigned short* __restrict__ V, unsigned short* __restrict__ Vt) {
    int bh = blockIdx.y;
    int sb = blockIdx.x * 64;
    size_t slab = (size_t)bh * SS * DH;
    __shared__ unsigned int tI[64][65];
    int tid = threadIdx.x;
    #pragma unroll
    for (int v = 0; v < 2; v++) {
        int c = tid + v * 256;
        int row = c >> 3, col = (c & 7) * 8;
        uint4 u = *(const uint4*)&V[slab + (size_t)(sb + row) * DH + col];
        const unsigned short* us = (const unsigned short*)&u;
        #pragma unroll
        for (int j = 0; j < 8; j++) tI[row][col + j] = us[j];
    }
    __syncthreads();
    #pragma unroll
    for (int v = 0; v < 2; v++) {
        int c = tid + v * 256;
        int drow = c >> 3, scol = (c & 7) * 8;
        unsigned short o[8];
        #pragma unroll
        for (int j = 0; j < 8; j++) o[j] = (unsigned short)tI[scol + j][drow];
        *(uint4*)&Vt[slab + (size_t)drow * SS + sb + scol] = *(uint4*)o;
    }
}

// ---------------- 128x128 MFMA GEMM: C = A @ Wt^T + bias (Wt is [n][k]) ----------------
// BK=64, double-buffered LDS via global_load_lds (pre-swizzled src), 1 barrier/k-step.
// XCD-chunked block swizzle: 24 (or 8) n-blocks of one m-panel land on one XCD.
__global__ __launch_bounds__(256, 2) void gemm_k(
    const unsigned short* __restrict__ A, const unsigned short* __restrict__ Wt,
    const float* __restrict__ b0, const float* __restrict__ b1, const float* __restrict__ b2,
    unsigned short* __restrict__ o16, float* __restrict__ o32, int mode)
{
    __shared__ __attribute__((aligned(16))) unsigned short lA[2][128 * 64];
    __shared__ __attribute__((aligned(16))) unsigned short lB[2][128 * 64];

    int tid = threadIdx.x;
    int wave = tid >> 6, lane = tid & 63, quad = lane >> 4, l16 = lane & 15;
    int wm = (wave & 1) * 64, wn = (wave >> 1) * 64;
    int srow = tid >> 3, scol = (tid & 7) * 8;
    int scolsw = scol ^ ((srow & 7) << 3);
    int wv = wave;

    // XCD-aware bijective swizzle (nwg % 8 == 0 for both grids)
    int gy = gridDim.y;
    int bid = blockIdx.y * gridDim.x + blockIdx.x;
    int chunk = (gridDim.x * gy) >> 3;
    int wgid = (bid & 7) * chunk + (bid >> 3);
    int mi_ = wgid / gy, nc = wgid - mi_ * gy;
    int mbase = mi_ * 128;

    int nbase;
    const float* bias;
    float scale = 1.0f;
    const unsigned short* W = Wt;
    unsigned short* oq = o16;
    if (mode == 1) {
        int widx = nc >> 3;                 // 0=Q 1=K 2=V
        nbase = (nc & 7) * 128;
        W = Wt + (size_t)widx * FF * FF;
        bias = (widx == 0) ? b0 : (widx == 1) ? b1 : b2;
        scale = (widx == 0) ? 0.015625f : 1.0f;
        oq = o16 + (size_t)widx * BB * SS * FF;
    } else {
        nbase = nc * 128;
        bias = b0;
    }

    f32x4 acc[4][4];
    #pragma unroll
    for (int i = 0; i < 4; i++)
        #pragma unroll
        for (int j = 0; j < 4; j++) acc[i][j] = (f32x4){0.f, 0.f, 0.f, 0.f};

    const unsigned short* gA = A + (size_t)(mbase + srow) * FF + scolsw;
    const unsigned short* gB = W + (size_t)(nbase + srow) * FF + scolsw;

    // stage k-tile 0 into buf 0
    #pragma unroll
    for (int i = 0; i < 4; i++) {
        async_copy16((void*)&lA[0][(i * 32 + wv * 8) * 64], gA + (size_t)i * 32 * FF);
        async_copy16((void*)&lB[0][(i * 32 + wv * 8) * 64], gB + (size_t)i * 32 * FF);
    }
    __syncthreads();

    for (int kt = 0; kt < 16; kt++) {
        int cur = kt & 1;
        if (kt < 15) {
            int kb = (kt + 1) * 64;
            #pragma unroll
            for (int i = 0; i < 4; i++) {
                async_copy16((void*)&lA[cur ^ 1][(i * 32 + wv * 8) * 64], gA + (size_t)i * 32 * FF + kb);
                async_copy16((void*)&lB[cur ^ 1][(i * 32 + wv * 8) * 64], gB + (size_t)i * 32 * FF + kb);
            }
        }
        #pragma unroll
        for (int ks = 0; ks < 2; ks++) {
            bf16x8 af[4], bfr[4];
            #pragma unroll
            for (int mi = 0; mi < 4; mi++) {
                int row = wm + mi * 16 + l16;
                af[mi] = *(const bf16x8*)(&lA[cur][row * 64 + sw(row, ks * 32 + quad * 8)]);
            }
            #pragma unroll
            for (int ni = 0; ni < 4; ni++) {
                int row = wn + ni * 16 + l16;
                bfr[ni] = *(const bf16x8*)(&lB[cur][row * 64 + sw(row, ks * 32 + quad * 8)]);
            }
            #pragma unroll
            for (int mi = 0; mi < 4; mi++)
                #pragma unroll
                for (int ni = 0; ni < 4; ni++)
                    acc[mi][ni] = __builtin_amdgcn_mfma_f32_16x16x32_bf16(af[mi], bfr[ni], acc[mi][ni], 0, 0, 0);
        }
        __syncthreads();   // drains vmcnt -> next buffer ready; reads of cur done
    }

    // epilogue
    #pragma unroll
    for (int mi = 0; mi < 4; mi++) {
        #pragma unroll
        for (int ni = 0; ni < 4; ni++) {
            int col = nbase + wn + ni * 16 + l16;
            float bv = bias[col];
            #pragma unroll
            for (int r = 0; r < 4; r++) {
                int row = mbase + wm + mi * 16 + quad * 4 + r;
                float v = (acc[mi][ni][r] + bv) * scale;
                if (mode == 1) {
                    int b_ = row >> 10, i = row & 1023;
                    int h = i >> 6, s_ = ((i & 63) << 4) + (col >> 6), d = col & 63;
                    oq[(((size_t)(b_ * HH + h)) * SS + s_) * DH + d] = f2b(v);
                } else {
                    o32[(size_t)row * FF + col] = v;
                }
            }
        }
    }
}

// ---------------- sm = softmax(masked str) as bf16, causal chunks only ----------------
// One wave per row. Reads only chunks i*256 <= r; writes those chunks (zeros beyond r).
__global__ void sm_k(const float* __restrict__ str, unsigned short* __restrict__ smq) {
    int row = blockIdx.x * 4 + (threadIdx.x >> 6);
    int lane = threadIdx.x & 63;
    int r = row & (SS - 1);
    int imax = r >> 8;
    const float* p = str + (size_t)row * SS;
    float vals[16];
    float mx = -1e30f;
    #pragma unroll
    for (int i = 0; i < 4; i++) {
        int k0 = i * 256 + lane * 4;
        if (i <= imax) {
            float4 u = *(const float4*)(&p[k0]);
            float uv[4] = {u.x, u.y, u.z, u.w};
            #pragma unroll
            for (int j = 0; j < 4; j++) {
                float v = (k0 + j <= r) ? uv[j] : -1e30f;
                vals[i * 4 + j] = v;
                mx = fmaxf(mx, v);
            }
        } else {
            #pragma unroll
            for (int j = 0; j < 4; j++) vals[i * 4 + j] = -1e30f;
        }
    }
    #pragma unroll
    for (int d = 1; d < 64; d <<= 1) mx = fmaxf(mx, __shfl_xor(mx, d));
    float sum = 0.f;
    #pragma unroll
    for (int t = 0; t < 16; t++) {
        float e = __expf(fminf(vals[t] - mx, 0.f));
        vals[t] = e;
        sum += e;
    }
    #pragma unroll
    for (int d = 1; d < 64; d <<= 1) sum += __shfl_xor(sum, d);
    float rinv = 1.0f / sum;
    unsigned short* q = smq + (size_t)row * SS;
    #pragma unroll
    for (int i = 0; i < 4; i++) {
        if (i <= imax) {
            ushort4 o;
            o.x = f2b(vals[i * 4 + 0] * rinv);
            o.y = f2b(vals[i * 4 + 1] * rinv);
            o.z = f2b(vals[i * 4 + 2] * rinv);
            o.w = f2b(vals[i * 4 + 3] * rinv);
            *(ushort4*)(&q[i * 256 + lane * 4]) = o;
        }
    }
}

// ---------------- fused attention ----------------
// Q prescaled by 1/64. scores = QK^T + sm(bf16, precomputed); online softmax; O = P@V.
// K/V staged via global_load_lds (pre-swizzled src), double-buffered, 1 barrier/tile.
__global__ __launch_bounds__(256, 4) void attn_k(
    const unsigned short* __restrict__ Q, const unsigned short* __restrict__ K,
    const unsigned short* __restrict__ Vt, const unsigned short* __restrict__ sm,
    unsigned short* __restrict__ ctx)
{
    int tid = threadIdx.x;
    int wave = tid >> 6, lane = tid & 63, quad = lane >> 4, l16 = lane & 15;
    int srow = tid >> 3, scol = (tid & 7) * 8;
    int scolsw = scol ^ ((srow & 7) << 3);
    int wv = wave;

    // XCD-chunked swizzle: 8 bh slabs per XCD (K/V/sm L2 locality)
    int bid = blockIdx.y * gridDim.x + blockIdx.x;   // 1024 blocks
    int wgid = (bid & 7) * 128 + (bid >> 3);
    int qb = wgid & 15, bh = wgid >> 4;
    int b_ = bh >> 4, h = bh & 15;
    int qbase = qb * 64;

    __shared__ __attribute__((aligned(16))) unsigned short lQP[64 * 64];   // Q staging, then P
    __shared__ __attribute__((aligned(16))) unsigned short lK[2][64 * 64];
    __shared__ __attribute__((aligned(16))) unsigned short lV[2][64 * 64]; // rows=d, cols=t

    const size_t slab = (size_t)bh * SS * DH;

    // prologue: Q plain-staged (swizzled store), K/V tile0 via async
    #pragma unroll
    for (int v = 0; v < 2; v++) {
        int row = srow + v * 32;
        *(uint4*)&lQP[row * 64 + sw(row, scol)] = *(const uint4*)&Q[slab + (size_t)(qbase + row) * DH + scol];
        async_copy16((void*)&lK[0][(v * 32 + wv * 8) * 64], &K [slab + (size_t)row * DH + scolsw]);
        async_copy16((void*)&lV[0][(v * 32 + wv * 8) * 64], &Vt[slab + (size_t)row * SS + scolsw]);
    }
    int q_loc0 = wave * 16 + quad * 4;
    __syncthreads();

    bf16x8 aq[2];
    #pragma unroll
    for (int ks = 0; ks < 2; ks++) {
        int row = wave * 16 + l16;
        aq[ks] = *(const bf16x8*)&lQP[row * 64 + sw(row, ks * 32 + quad * 8)];
    }

    float m_st[4], l_st[4];
    f32x4 Oacc[4];
    #pragma unroll
    for (int r = 0; r < 4; r++) { m_st[r] = -1e30f; l_st[r] = 0.f; }
    #pragma unroll
    for (int ni = 0; ni < 4; ni++) Oacc[ni] = (f32x4){0.f, 0.f, 0.f, 0.f};

    const size_t smbase = (size_t)bh * SS * SS;
    unsigned short* lPw = &lQP[(wave * 16) * 64];

    for (int tt = 0; tt < 16; tt++) {
        int cur = tt & 1;
        int tbase = tt * 64;
        bool need_sm = (tbase <= qbase);   // block-uniform (both multiples of 64)

        // next-tile K/V async staging (in flight across this tile's compute)
        if (tt < 15) {
            int nb = tbase + 64;
            #pragma unroll
            for (int v = 0; v < 2; v++) {
                int row = srow + v * 32;
                async_copy16((void*)&lK[cur ^ 1][(v * 32 + wv * 8) * 64], &K [slab + (size_t)(nb + row) * DH + scolsw]);
                async_copy16((void*)&lV[cur ^ 1][(v * 32 + wv * 8) * 64], &Vt[slab + (size_t)row * SS + nb + scolsw]);
            }
        }
        // sm loads for this tile (bf16; exact zeros where masked)
        float sf[4][4];
        if (need_sm) {
            #pragma unroll
            for (int r = 0; r < 4; r++) {
                int q_abs = qbase + q_loc0 + r;
                const unsigned short* pr = sm + smbase + (size_t)q_abs * SS + tbase + l16;
                #pragma unroll
                for (int ni = 0; ni < 4; ni++)
                    sf[ni][r] = b2f(pr[ni * 16]);
            }
        }

        // S = Q @ K^T  (16x64 per wave)
        f32x4 sa[4];
        #pragma unroll
        for (int ni = 0; ni < 4; ni++) sa[ni] = (f32x4){0.f, 0.f, 0.f, 0.f};
        #pragma unroll
        for (int ks = 0; ks < 2; ks++) {
            #pragma unroll
            for (int ni = 0; ni < 4; ni++) {
                int row = ni * 16 + l16;
                bf16x8 bk_ = *(const bf16x8*)&lK[cur][row * 64 + sw(row, ks * 32 + quad * 8)];
                sa[ni] = __builtin_amdgcn_mfma_f32_16x16x32_bf16(aq[ks], bk_, sa[ni], 0, 0, 0);
            }
        }

        // scores = S + sm ; online softmax
        float tm[4];
        #pragma unroll
        for (int r = 0; r < 4; r++) tm[r] = -1e30f;
        #pragma unroll
        for (int ni = 0; ni < 4; ni++) {
            #pragma unroll
            for (int r = 0; r < 4; r++) {
                float v = sa[ni][r];
                if (need_sm) v += sf[ni][r];
                sa[ni][r] = v;
                tm[r] = fmaxf(tm[r], v);
            }
        }
        #pragma unroll
        for (int r = 0; r < 4; r++) {
            float v = tm[r];
            v = fmaxf(v, __shfl_xor(v, 1));
            v = fmaxf(v, __shfl_xor(v, 2));
            v = fmaxf(v, __shfl_xor(v, 4));
            v = fmaxf(v, __shfl_xor(v, 8));
            tm[r] = v;
        }
        float alpha[4], rs[4];
        #pragma unroll
        for (int r = 0; r < 4; r++) {
            float mn = fmaxf(m_st[r], tm[r]);
            alpha[r] = __expf(fminf(m_st[r] - mn, 0.f));
            m_st[r] = mn;
            rs[r] = 0.f;
        }
        #pragma unroll
        for (int ni = 0; ni < 4; ni++)
            #pragma unroll
            for (int r = 0; r < 4; r++) {
                sa[ni][r] = __expf(fminf(sa[ni][r] - m_st[r], 0.f));
                rs[r] += sa[ni][r];
            }
        #pragma unroll
        for (int r = 0; r < 4; r++) {
            float v = rs[r];
            v += __shfl_xor(v, 1); v += __shfl_xor(v, 2);
            v += __shfl_xor(v, 4); v += __shfl_xor(v, 8);
            l_st[r] = l_st[r] * alpha[r] + v;
        }
        #pragma unroll
        for (int ni = 0; ni < 4; ni++)
            #pragma unroll
            for (int r = 0; r < 4; r++) Oacc[ni][r] *= alpha[r];

        // P -> LDS (wave-private rows; swizzled by local row)
        #pragma unroll
        for (int ni = 0; ni < 4; ni++)
            #pragma unroll
            for (int r = 0; r < 4; r++) {
                int pr = quad * 4 + r;
                lPw[pr * 64 + sw(pr, ni * 16 + l16)] = f2b(sa[ni][r]);
            }

        // O += P @ V
        #pragma unroll
        for (int ks = 0; ks < 2; ks++) {
            bf16x8 pa = *(const bf16x8*)&lPw[l16 * 64 + sw(l16, ks * 32 + quad * 8)];
            #pragma unroll
            for (int ni = 0; ni < 4; ni++) {
                int row = ni * 16 + l16;
                bf16x8 bv = *(const bf16x8*)&lV[cur][row * 64 + sw(row, ks * 32 + quad * 8)];
                Oacc[ni] = __builtin_amdgcn_mfma_f32_16x16x32_bf16(pa, bv, Oacc[ni], 0, 0, 0);
            }
        }

        __syncthreads();   // drains vmcnt (next K/V landed) + lgkmcnt
    }

    // epilogue: ctx[b][s][h*64+d]
    #pragma unroll
    for (int r = 0; r < 4; r++) {
        int s_abs = qbase + wave * 16 + quad * 4 + r;
        float li = 1.0f / l_st[r];
        #pragma unroll
        for (int ni = 0; ni < 4; ni++) {
            int d = ni * 16 + l16;
            ctx[((size_t)b_ * SS + s_abs) * FF + h * 64 + d] = f2b(Oacc[ni][r] * li);
        }
    }
}

extern "C" void kernel_launch(void* const* d_in, const int* in_sizes, int n_in,
                              void* d_out, int out_size, void* d_ws, size_t ws_size,
                              hipStream_t stream) {
    const float* x   = (const float*)d_in[0];
    const float* str = (const float*)d_in[1];
    const float* Wq  = (const float*)d_in[3];
    const float* bq  = (const float*)d_in[4];
    const float* Wk  = (const float*)d_in[5];
    const float* bk  = (const float*)d_in[6];
    const float* Wv  = (const float*)d_in[7];
    const float* bv  = (const float*)d_in[8];
    const float* Wo  = (const float*)d_in[9];
    const float* bo  = (const float*)d_in[10];

    // workspace layout:
    //   xb   : [0, 8) MB        Wb : [8, 16) MB       QKV: [16, 40) MB
    //   Vt   : [40, 48) MB      ctx: [48, 56) MB      sm : [64, 192) MB (bf16 [bh][q][k])
    char* ws = (char*)d_ws;
    const size_t MB = 1024ull * 1024;
    unsigned short* xb  = (unsigned short*)ws;
    unsigned short* Wb  = (unsigned short*)(ws + 8 * MB);
    unsigned short* QKV = (unsigned short*)(ws + 16 * MB);
    unsigned short* Vtp = (unsigned short*)(ws + 40 * MB);
    unsigned short* ctx = (unsigned short*)(ws + 48 * MB);
    unsigned short* smb = (unsigned short*)(ws + 64 * MB);

    const size_t QN = (size_t)BB * SS * FF;   // 4M elems
    const size_t WN = (size_t)FF * FF;        // 1M elems

    cvt_k<<<4096, 256, 0, stream>>>(x, xb, (int)QN);
    cvtT_k<<<dim3(1024, 4), 256, 0, stream>>>(Wq, Wk, Wv, Wo, Wb);

    gemm_k<<<dim3(32, 24), 256, 0, stream>>>(xb, Wb, bq, bk, bv, QKV, nullptr, 1);
    vtrans_k<<<dim3(16, 64), 256, 0, stream>>>(QKV + 2 * QN, Vtp);
    sm_k<<<16384, 256, 0, stream>>>(str, smb);
    attn_k<<<dim3(16, 64), 256, 0, stream>>>(QKV, QKV + QN, Vtp, smb, ctx);
    gemm_k<<<dim3(32, 8), 256, 0, stream>>>(ctx, Wb + 3 * WN, bo, nullptr, nullptr, nullptr, (float*)d_out, 0);
}